// Round 1
// baseline (49.867 us; speedup 1.0000x reference)
//
#include <hip/hip_runtime.h>

// Problem dims (fixed by the reference)
#define BSZ 32
#define SEQ 512
#define LW  16      // chars per word (max)
#define GD  300     // glove dim
#define CEM 64      // char emb dim
#define OD  100     // out dim of conv/linear
#define NW  (BSZ * SEQ)   // 16384 words

// Precompute fused weight W[e][o] = sum_j lin_w[o,j] * conv_w[j,e]   (64 x 100)
// and fused bias      c[o]   = lin_b[o] + sum_j lin_w[o,j] * conv_b[j]
// into d_ws: [0 .. 6400) = W row-major [e][o], [6400 .. 6500) = c
__global__ void precompute_Wc(const float* __restrict__ conv_w,
                              const float* __restrict__ conv_b,
                              const float* __restrict__ lin_w,
                              const float* __restrict__ lin_b,
                              float* __restrict__ Wc) {
    int idx = blockIdx.x * blockDim.x + threadIdx.x;
    if (idx < CEM * OD) {
        int e = idx / OD;
        int o = idx % OD;
        float s = 0.f;
        for (int j = 0; j < OD; ++j)
            s = fmaf(lin_w[o * OD + j], conv_w[j * CEM + e], s);
        Wc[idx] = s;
    } else if (idx < CEM * OD + OD) {
        int o = idx - CEM * OD;
        float s = lin_b[o];
        for (int j = 0; j < OD; ++j)
            s = fmaf(lin_w[o * OD + j], conv_b[j], s);
        Wc[CEM * OD + o] = s;
    }
}

// One wave (64 lanes) per word. 4 waves / block.
__global__ __launch_bounds__(256) void fused_embed(
        const int*   __restrict__ word_tokens,
        const int*   __restrict__ char_ids,
        const int*   __restrict__ char_lens,
        const float* __restrict__ glove,
        const float* __restrict__ char_table,
        const float* __restrict__ Wc,
        float*       __restrict__ out) {
    __shared__ float mce[4][CEM];

    const int wave = threadIdx.x >> 6;
    const int lane = threadIdx.x & 63;
    const int word = blockIdx.x * 4 + wave;

    // ---- glove gather-copy: 300 floats = 75 float4, coalesced ----
    const int tok = word_tokens[word];
    const float4* g4 = (const float4*)(glove + (size_t)tok * GD);
    float4*       d4 = (float4*)(out + (size_t)word * (GD + OD));
    for (int i = lane; i < GD / 4; i += 64)
        d4[i] = g4[i];

    // ---- masked mean over chars: lane = embedding dim e ----
    const int len = char_lens[word];          // >= 1 guaranteed
    const int* cid = char_ids + word * LW;
    float acc = 0.f;
    for (int l = 0; l < len; ++l) {
        int ch = cid[l];                      // wave-uniform load (L1 hit)
        acc += char_table[ch * CEM + lane];   // coalesced 256B row
    }
    acc *= 1.f / (float)len;
    mce[wave][lane] = acc;
    __syncthreads();

    // ---- fused matvec: out[o] = sum_e mce[e] * W[e][o] + c[o] ----
    const float* m = mce[wave];
    float s0 = Wc[CEM * OD + lane];                       // c[lane]
    float s1 = (lane < OD - 64) ? Wc[CEM * OD + 64 + lane] : 0.f;
    for (int e = 0; e < CEM; ++e) {
        float me = m[e];                                  // LDS broadcast
        s0 = fmaf(me, Wc[e * OD + lane], s0);             // coalesced
        if (lane < OD - 64)
            s1 = fmaf(me, Wc[e * OD + 64 + lane], s1);
    }
    float* co = out + (size_t)word * (GD + OD) + GD;
    co[lane] = s0;
    if (lane < OD - 64)
        co[64 + lane] = s1;
}

extern "C" void kernel_launch(void* const* d_in, const int* in_sizes, int n_in,
                              void* d_out, int out_size, void* d_ws, size_t ws_size,
                              hipStream_t stream) {
    const int*   word_tokens = (const int*)  d_in[0];
    const int*   char_ids    = (const int*)  d_in[1];
    const int*   char_lens   = (const int*)  d_in[2];
    const float* glove       = (const float*)d_in[3];
    const float* char_table  = (const float*)d_in[4];
    const float* conv_w      = (const float*)d_in[5];
    const float* conv_b      = (const float*)d_in[6];
    const float* lin_w       = (const float*)d_in[7];
    const float* lin_b       = (const float*)d_in[8];
    float* out = (float*)d_out;
    float* Wc  = (float*)d_ws;   // 6500 floats = 26 KB scratch

    precompute_Wc<<<(CEM * OD + OD + 255) / 256, 256, 0, stream>>>(
        conv_w, conv_b, lin_w, lin_b, Wc);

    fused_embed<<<NW / 4, 256, 0, stream>>>(
        word_tokens, char_ids, char_lens, glove, char_table, Wc, out);
}

// Round 2
// 34.339 us; speedup vs baseline: 1.4522x; 1.4522x over previous
//
#include <hip/hip_runtime.h>

// Problem dims (fixed by the reference)
#define BSZ 32
#define SEQ 512
#define LW  16      // chars per word (max)
#define GD  300     // glove dim
#define CEM 64      // char emb dim
#define OD  100     // out dim of conv/linear
#define NW  (BSZ * SEQ)   // 16384 words

// Wc layout in d_ws: [0 .. 6400) = W[e][o] row-major, [6400 .. 6500) = c[o]
//   W[e][o] = sum_j lin_w[o,j] * conv_w[j,e]
//   c[o]    = lin_b[o] + sum_j lin_w[o,j] * conv_b[j]
// Grid: 65 blocks (e = 0..63 -> W row e; block 64 -> bias c), 128 threads, lane = o.
__global__ __launch_bounds__(128) void precompute_Wc(
        const float* __restrict__ conv_w, const float* __restrict__ conv_b,
        const float* __restrict__ lin_w,  const float* __restrict__ lin_b,
        float* __restrict__ Wc) {
    const int o = threadIdx.x;
    if (o >= OD) return;
    const int e = blockIdx.x;
    const float* lw = lin_w + o * OD;
    if (e < CEM) {
        float a0 = 0.f, a1 = 0.f, a2 = 0.f, a3 = 0.f;
        #pragma unroll 5
        for (int j = 0; j < OD; j += 4) {
            a0 = fmaf(lw[j + 0], conv_w[(j + 0) * CEM + e], a0);  // conv_w read is wave-uniform
            a1 = fmaf(lw[j + 1], conv_w[(j + 1) * CEM + e], a1);
            a2 = fmaf(lw[j + 2], conv_w[(j + 2) * CEM + e], a2);
            a3 = fmaf(lw[j + 3], conv_w[(j + 3) * CEM + e], a3);
        }
        Wc[e * OD + o] = (a0 + a1) + (a2 + a3);                    // coalesced store
    } else {
        float a0 = lin_b[o], a1 = 0.f, a2 = 0.f, a3 = 0.f;
        #pragma unroll 5
        for (int j = 0; j < OD; j += 4) {
            a0 = fmaf(lw[j + 0], conv_b[j + 0], a0);
            a1 = fmaf(lw[j + 1], conv_b[j + 1], a1);
            a2 = fmaf(lw[j + 2], conv_b[j + 2], a2);
            a3 = fmaf(lw[j + 3], conv_b[j + 3], a3);
        }
        Wc[CEM * OD + o] = (a0 + a1) + (a2 + a3);
    }
}

// One wave (64 lanes) per word, 4 waves / block.
__global__ __launch_bounds__(256) void fused_embed(
        const int*   __restrict__ word_tokens,
        const int*   __restrict__ char_ids,
        const int*   __restrict__ char_lens,
        const float* __restrict__ glove,
        const float* __restrict__ char_table,
        const float* __restrict__ Wc,
        float*       __restrict__ out) {
    __shared__ float mce[4][CEM];

    const int wave = threadIdx.x >> 6;
    const int lane = threadIdx.x & 63;
    const int word = blockIdx.x * 4 + wave;

    // ---- issue ALL independent loads up front ----
    const int tok = word_tokens[word];
    const int len = char_lens[word];

    const float4* g4 = (const float4*)(glove + (size_t)tok * GD);
    float4 g0 = g4[lane];                                   // 75 float4 total
    float4 g1;
    const bool tail = lane < (GD / 4 - 64);                 // lanes 0..10
    if (tail) g1 = g4[64 + lane];

    const int4* cid4 = (const int4*)(char_ids + (size_t)word * LW);
    int4 c0 = cid4[0], c1 = cid4[1], c2 = cid4[2], c3 = cid4[3];
    const int ids[LW] = {c0.x, c0.y, c0.z, c0.w, c1.x, c1.y, c1.z, c1.w,
                         c2.x, c2.y, c2.z, c2.w, c3.x, c3.y, c3.z, c3.w};

    // ---- masked mean: 16 independent L1-resident row loads, 4 partial sums ----
    float a0 = 0.f, a1 = 0.f, a2 = 0.f, a3 = 0.f;
    #pragma unroll
    for (int l = 0; l < LW; l += 4) {
        float v0 = char_table[ids[l + 0] * CEM + lane];     // always-valid ids; mask after
        float v1 = char_table[ids[l + 1] * CEM + lane];
        float v2 = char_table[ids[l + 2] * CEM + lane];
        float v3 = char_table[ids[l + 3] * CEM + lane];
        a0 += (l + 0 < len) ? v0 : 0.f;
        a1 += (l + 1 < len) ? v1 : 0.f;
        a2 += (l + 2 < len) ? v2 : 0.f;
        a3 += (l + 3 < len) ? v3 : 0.f;
    }
    mce[wave][lane] = ((a0 + a1) + (a2 + a3)) * (1.f / (float)len);

    // ---- glove passthrough (coalesced float4) ----
    float4* d4 = (float4*)(out + (size_t)word * (GD + OD));
    d4[lane] = g0;
    if (tail) d4[64 + lane] = g1;

    __syncthreads();

    // ---- fused matvec: out[o] = c[o] + sum_e mce[e] * W[e][o] ----
    const float4* m4 = (const float4*)mce[wave];
    float s0 = Wc[CEM * OD + lane];                          // c[lane]
    float s1 = (lane < OD - 64) ? Wc[CEM * OD + 64 + lane] : 0.f;
    #pragma unroll 4
    for (int e4 = 0; e4 < CEM / 4; ++e4) {
        float4 mv = m4[e4];                                  // LDS b128 broadcast
        const float* w = Wc + e4 * 4 * OD;
        s0 = fmaf(mv.x, w[lane],            s0);             // L1-resident, coalesced
        s1 = fmaf(mv.x, w[64 + lane],       s1);             // max idx 6427 < 6500: in bounds
        s0 = fmaf(mv.y, w[OD + lane],       s0);
        s1 = fmaf(mv.y, w[OD + 64 + lane],  s1);
        s0 = fmaf(mv.z, w[2 * OD + lane],      s0);
        s1 = fmaf(mv.z, w[2 * OD + 64 + lane], s1);
        s0 = fmaf(mv.w, w[3 * OD + lane],      s0);
        s1 = fmaf(mv.w, w[3 * OD + 64 + lane], s1);
    }
    float* co = out + (size_t)word * (GD + OD) + GD;
    co[lane] = s0;
    if (lane < OD - 64) co[64 + lane] = s1;
}

extern "C" void kernel_launch(void* const* d_in, const int* in_sizes, int n_in,
                              void* d_out, int out_size, void* d_ws, size_t ws_size,
                              hipStream_t stream) {
    const int*   word_tokens = (const int*)  d_in[0];
    const int*   char_ids    = (const int*)  d_in[1];
    const int*   char_lens   = (const int*)  d_in[2];
    const float* glove       = (const float*)d_in[3];
    const float* char_table  = (const float*)d_in[4];
    const float* conv_w      = (const float*)d_in[5];
    const float* conv_b      = (const float*)d_in[6];
    const float* lin_w       = (const float*)d_in[7];
    const float* lin_b       = (const float*)d_in[8];
    float* out = (float*)d_out;
    float* Wc  = (float*)d_ws;   // 6500 floats = 26 KB scratch

    precompute_Wc<<<CEM + 1, 128, 0, stream>>>(conv_w, conv_b, lin_w, lin_b, Wc);

    fused_embed<<<NW / 4, 256, 0, stream>>>(
        word_tokens, char_ids, char_lens, glove, char_table, Wc, out);
}